// Round 3
// baseline (71.358 us; speedup 1.0000x reference)
//
#include <hip/hip_runtime.h>

// ---------------- types / helpers ----------------
using f32x4  = __attribute__((ext_vector_type(4))) float;
using bf16x8 = __attribute__((ext_vector_type(8))) short;

struct __attribute__((packed, aligned(4))) f4a { float x, y, z, w; };  // 4B-aligned float4

__device__ __forceinline__ unsigned short f2bf(float x) {
  unsigned u = __float_as_uint(x);
  u += 0x7FFFu + ((u >> 16) & 1u);   // round-to-nearest-even
  return (unsigned short)(u >> 16);
}

// pc1: (8,1024,259)  pc2: (8,4096,131)  W1:(384,256) b1:(256) W2:(256,256) b2:(256)
// out: h (8*4096*256 fp32) then xyz2 (8*4096*3 fp32)
#define OUT_H_ELEMS 8388608

// ---------------- front: weights cvt + 3-NN + inline interp + pc2 cols + xyz2 ----------------
// 1024 blocks x 256 threads; 8 threads per query point (32 queries/block).
#define INSERT(e, j) { \
  bool L2 = ((e) < d2v) || ((e) == d2v && (j) < i2); \
  bool L1 = ((e) < d1 ) || ((e) == d1  && (j) < i1); \
  bool L0 = ((e) < d0 ) || ((e) == d0  && (j) < i0); \
  d2v = L1 ? d1 : (L2 ? (e) : d2v);  i2 = L1 ? i1 : (L2 ? (j) : i2); \
  d1  = L0 ? d0 : (L1 ? (e) : d1 );  i1 = L0 ? i0 : (L1 ? (j) : i1); \
  d0  = L0 ? (e) : d0;               i0 = L0 ? (j) : i0; }

__global__ void front(const float* __restrict__ pc1, const float* __restrict__ pc2,
                      const float* __restrict__ W1, const float* __restrict__ W2,
                      unsigned short* __restrict__ W1t, unsigned short* __restrict__ W2t,
                      unsigned short* __restrict__ A1, float* __restrict__ xyzo) {
  __shared__ float4 s[1024];
  const int t = threadIdx.x;
  const int blk = blockIdx.x;
  const int b = blk >> 7;            // 8 batches x 128 blocks
  const int chunk = blk & 127;       // 32 queries per block

  // --- weight conversion: 1 element per thread across first 163840 global threads ---
  int gid = blk * 256 + t;
  if (gid < 98304) {                           // W1t[n][k] = W1[k][n], 256x384
    int n = gid / 384, k = gid - n * 384;
    W1t[gid] = f2bf(W1[k * 256 + n]);
  } else if (gid < 163840) {                   // W2t[n][k] = W2[k][n], 256x256
    int id2 = gid - 98304;
    int n = id2 >> 8, k = id2 & 255;
    W2t[id2] = f2bf(W2[k * 256 + n]);
  }

  // --- stage xyz1 of this batch into LDS ---
  const float* p1b = pc1 + (size_t)b * (1024 * 259);
  #pragma unroll
  for (int j = 0; j < 4; ++j) {
    int r = t + j * 256;
    const float* p = p1b + (size_t)r * 259;
    s[r] = make_float4(p[0], p[1], p[2], 0.f);
  }
  __syncthreads();

  const int q = chunk * 32 + (t >> 3);         // query index within batch
  const int sub = t & 7;
  const size_t qrow = (size_t)b * 4096 + q;
  const float* qp = pc2 + qrow * 131;
  const float qx = qp[0], qy = qp[1], qz = qp[2];

  float d0 = 3.4e38f, d1 = 3.4e38f, d2v = 3.4e38f;
  int i0 = -1, i1 = -1, i2 = -1;
  #pragma unroll 4
  for (int it = 0; it < 128; ++it) {
    const int c = sub + it * 8;
    float4 p = s[c];
    // match numpy: ((dx*dx + dy*dy) + dz*dz), no FMA contraction
    float dx = __fsub_rn(qx, p.x);
    float dy = __fsub_rn(qy, p.y);
    float dz = __fsub_rn(qz, p.z);
    float d = __fadd_rn(__fadd_rn(__fmul_rn(dx, dx), __fmul_rn(dy, dy)), __fmul_rn(dz, dz));
    bool l2 = d < d2v, l1 = d < d1, l0 = d < d0;   // strict < keeps earlier index on ties
    d2v = l1 ? d1 : (l2 ? d : d2v);  i2 = l1 ? i1 : (l2 ? c : i2);
    d1  = l0 ? d0 : (l1 ? d : d1);   i1 = l0 ? i0 : (l1 ? c : i1);
    d0  = l0 ? d  : d0;              i0 = l0 ? c  : i0;
  }
  // merge across the 8 lanes of this query (xor 1,2,4); all lanes end identical
  #pragma unroll
  for (int stp = 1; stp <= 4; stp <<= 1) {
    float e0 = __shfl_xor(d0, stp, 64);  int j0 = __shfl_xor(i0, stp, 64);
    float e1 = __shfl_xor(d1, stp, 64);  int j1 = __shfl_xor(i1, stp, 64);
    float e2 = __shfl_xor(d2v, stp, 64); int j2 = __shfl_xor(i2, stp, 64);
    INSERT(e0, j0) INSERT(e1, j1) INSERT(e2, j2)
  }
  // weights (exact reference order)
  float t0 = fmaxf(d0, 1e-7f), t1 = fmaxf(d1, 1e-7f), t2 = fmaxf(d2v, 1e-7f);
  float r0 = 1.0f / t0, r1 = 1.0f / t1, r2 = 1.0f / t2;
  float nrm = __fadd_rn(__fadd_rn(r0, r1), r2);
  float w0v = r0 / nrm, w1v = r1 / nrm, w2v = r2 / nrm;

  if (sub == 1) {
    xyzo[qrow * 3 + 0] = qx; xyzo[qrow * 3 + 1] = qy; xyzo[qrow * 3 + 2] = qz;
  }

  // --- inline interpolation: lane sub covers interp cols [sub*32, sub*32+32) ---
  const float* g0p = p1b + (size_t)i0 * 259 + 3 + sub * 32;
  const float* g1p = p1b + (size_t)i1 * 259 + 3 + sub * 32;
  const float* g2p = p1b + (size_t)i2 * 259 + 3 + sub * 32;
  unsigned short* arow = A1 + qrow * 384 + sub * 32;
  #pragma unroll
  for (int c4 = 0; c4 < 8; ++c4) {
    f4a a0 = *(const f4a*)(g0p + c4 * 4);
    f4a a1 = *(const f4a*)(g1p + c4 * 4);
    f4a a2 = *(const f4a*)(g2p + c4 * 4);
    ushort4 ov;
    ov.x = f2bf(fmaf(w2v, a2.x, fmaf(w1v, a1.x, w0v * a0.x)));
    ov.y = f2bf(fmaf(w2v, a2.y, fmaf(w1v, a1.y, w0v * a0.y)));
    ov.z = f2bf(fmaf(w2v, a2.z, fmaf(w1v, a1.z, w0v * a0.z)));
    ov.w = f2bf(fmaf(w2v, a2.w, fmaf(w1v, a1.w, w0v * a0.w)));
    *(ushort4*)(arow + c4 * 4) = ov;
  }
  // --- pc2 feature cols: lane sub covers A1 cols [256+sub*16, 256+sub*16+16) ---
  const float* gp = qp + 3 + sub * 16;
  unsigned short* arow2 = A1 + qrow * 384 + 256 + sub * 16;
  #pragma unroll
  for (int c4 = 0; c4 < 4; ++c4) {
    f4a v = *(const f4a*)(gp + c4 * 4);
    ushort4 ov;
    ov.x = f2bf(v.x); ov.y = f2bf(v.y); ov.z = f2bf(v.z); ov.w = f2bf(v.w);
    *(ushort4*)(arow2 + c4 * 4) = ov;
  }
}

// ---------------- fused two-layer MFMA GEMM (unchanged from R2, verified) ----------------
__global__ __launch_bounds__(512, 2) void fused_gemm(
    const unsigned short* __restrict__ A1, const unsigned short* __restrict__ W1t,
    const unsigned short* __restrict__ W2t, const float* __restrict__ b1,
    const float* __restrict__ b2, float* __restrict__ out) {
  extern __shared__ char lds[];
  char* Hbuf = lds;                       // [0, 64K): H tile 128x256 bf16, row stride 512B
  char* Bb[2] = { lds + 65536, lds + 98304 };
  char* Ab[2] = { lds + 131072, lds + 147456 };

  const int t = threadIdx.x, lane = t & 63, wv = t >> 6;
  const int wm = wv >> 2, wn = wv & 3;
  const int m0 = blockIdx.x * 128;

  const int arow = t >> 2, as0 = (t & 3) * 2;
  const int brow = t >> 1, bs0 = (t & 1) * 4;
  const unsigned short* gA  = A1  + (size_t)(m0 + arow) * 384 + as0 * 8;
  const unsigned short* gB1 = W1t + (size_t)brow * 384 + bs0 * 8;
  const unsigned short* gW2 = W2t + (size_t)brow * 256 + bs0 * 8;
  int awo[2], bwo[4];
  #pragma unroll
  for (int j = 0; j < 2; ++j)
    awo[j] = arow * 128 + (((as0 + j) * 16) ^ ((arow & 7) << 4));
  #pragma unroll
  for (int j = 0; j < 4; ++j)
    bwo[j] = brow * 128 + (((bs0 + j) * 16) ^ ((brow & 7) << 4));

  f32x4 zero = {0.f, 0.f, 0.f, 0.f};
  f32x4 acc[4][4];
  #pragma unroll
  for (int i = 0; i < 4; ++i)
    #pragma unroll
    for (int j = 0; j < 4; ++j) acc[i][j] = zero;

  f32x4 ra[2], rb[4];
  #pragma unroll
  for (int j = 0; j < 2; ++j) ra[j] = *(const f32x4*)(const void*)(gA + j * 8);
  #pragma unroll
  for (int j = 0; j < 4; ++j) rb[j] = *(const f32x4*)(const void*)(gB1 + j * 8);
  #pragma unroll
  for (int j = 0; j < 2; ++j) *(f32x4*)(void*)(Ab[0] + awo[j]) = ra[j];
  #pragma unroll
  for (int j = 0; j < 4; ++j) *(f32x4*)(void*)(Bb[0] + bwo[j]) = rb[j];
  __syncthreads();

  int cur = 0;
  #pragma unroll
  for (int kt = 0; kt < 6; ++kt) {
    if (kt < 5) {
      #pragma unroll
      for (int j = 0; j < 2; ++j) ra[j] = *(const f32x4*)(const void*)(gA + (kt + 1) * 64 + j * 8);
      #pragma unroll
      for (int j = 0; j < 4; ++j) rb[j] = *(const f32x4*)(const void*)(gB1 + (kt + 1) * 64 + j * 8);
    }
    #pragma unroll
    for (int ks = 0; ks < 2; ++ks) {
      bf16x8 af[4], bfr[4];
      const int sl = ks * 4 + (lane >> 4);
      #pragma unroll
      for (int i = 0; i < 4; ++i) {
        int ar = wm * 64 + i * 16 + (lane & 15);
        af[i] = *(const bf16x8*)(void*)(Ab[cur] + ar * 128 + ((sl * 16) ^ ((ar & 7) << 4)));
        int br = wn * 64 + i * 16 + (lane & 15);
        bfr[i] = *(const bf16x8*)(void*)(Bb[cur] + br * 128 + ((sl * 16) ^ ((br & 7) << 4)));
      }
      #pragma unroll
      for (int i = 0; i < 4; ++i)
        #pragma unroll
        for (int j = 0; j < 4; ++j)
          acc[i][j] = __builtin_amdgcn_mfma_f32_16x16x32_bf16(af[i], bfr[j], acc[i][j], 0, 0, 0);
    }
    if (kt < 5) {
      #pragma unroll
      for (int j = 0; j < 2; ++j) *(f32x4*)(void*)(Ab[cur ^ 1] + awo[j]) = ra[j];
      #pragma unroll
      for (int j = 0; j < 4; ++j) *(f32x4*)(void*)(Bb[cur ^ 1] + bwo[j]) = rb[j];
    }
    __syncthreads();
    cur ^= 1;
  }

  const int colb = wn * 64 + (lane & 15);
  const int rowb = wm * 64 + ((lane >> 4) << 2);
  #pragma unroll
  for (int ni = 0; ni < 4; ++ni) {
    float bv = b1[colb + ni * 16];
    #pragma unroll
    for (int mi = 0; mi < 4; ++mi) {
      #pragma unroll
      for (int r = 0; r < 4; ++r) {
        float v = fmaxf(acc[mi][ni][r] + bv, 0.0f);
        int row = rowb + mi * 16 + r, col = colb + ni * 16;
        *(unsigned short*)(Hbuf + row * 512 + ((col * 2) ^ ((row & 15) << 4))) = f2bf(v);
        acc[mi][ni][r] = 0.0f;
      }
    }
  }
  #pragma unroll
  for (int j = 0; j < 4; ++j) rb[j] = *(const f32x4*)(const void*)(gW2 + j * 8);
  #pragma unroll
  for (int j = 0; j < 4; ++j) *(f32x4*)(void*)(Bb[0] + bwo[j]) = rb[j];
  __syncthreads();

  cur = 0;
  #pragma unroll
  for (int kt = 0; kt < 4; ++kt) {
    if (kt < 3) {
      #pragma unroll
      for (int j = 0; j < 4; ++j) rb[j] = *(const f32x4*)(const void*)(gW2 + (kt + 1) * 64 + j * 8);
    }
    #pragma unroll
    for (int ks = 0; ks < 2; ++ks) {
      bf16x8 af[4], bfr[4];
      const int sl = ks * 4 + (lane >> 4);
      #pragma unroll
      for (int i = 0; i < 4; ++i) {
        int hr = wm * 64 + i * 16 + (lane & 15);
        af[i] = *(const bf16x8*)(void*)(Hbuf + hr * 512 + ((kt * 128 + sl * 16) ^ ((hr & 15) << 4)));
        int wr = wn * 64 + i * 16 + (lane & 15);
        bfr[i] = *(const bf16x8*)(void*)(Bb[cur] + wr * 128 + ((sl * 16) ^ ((wr & 7) << 4)));
      }
      #pragma unroll
      for (int i = 0; i < 4; ++i)
        #pragma unroll
        for (int j = 0; j < 4; ++j)
          acc[i][j] = __builtin_amdgcn_mfma_f32_16x16x32_bf16(af[i], bfr[j], acc[i][j], 0, 0, 0);
    }
    if (kt < 3) {
      #pragma unroll
      for (int j = 0; j < 4; ++j) *(f32x4*)(void*)(Bb[cur ^ 1] + bwo[j]) = rb[j];
    }
    __syncthreads();
    cur ^= 1;
  }

  #pragma unroll
  for (int ni = 0; ni < 4; ++ni) {
    float bv = b2[colb + ni * 16];
    #pragma unroll
    for (int mi = 0; mi < 4; ++mi) {
      #pragma unroll
      for (int r = 0; r < 4; ++r) {
        float v = fmaxf(acc[mi][ni][r] + bv, 0.0f);
        int row = rowb + mi * 16 + r, col = colb + ni * 16;
        *(float*)(lds + row * 1024 + ((col * 4) ^ ((row & 15) << 4))) = v;
      }
    }
  }
  __syncthreads();
  #pragma unroll
  for (int q = 0; q < 16; ++q) {
    int row = q * 8 + wv;
    f32x4 v = *(const f32x4*)(void*)(lds + row * 1024 + ((lane * 16) ^ ((row & 15) << 4)));
    *(f32x4*)(out + (size_t)(m0 + row) * 256 + lane * 4) = v;
  }
}

// ---------------- launch ----------------
extern "C" void kernel_launch(void* const* d_in, const int* in_sizes, int n_in,
                              void* d_out, int out_size, void* d_ws, size_t ws_size,
                              hipStream_t stream) {
  const float* pc1 = (const float*)d_in[0];
  const float* pc2 = (const float*)d_in[1];
  const float* W1  = (const float*)d_in[2];
  const float* b1  = (const float*)d_in[3];
  const float* W2  = (const float*)d_in[4];
  const float* b2  = (const float*)d_in[5];
  float* out = (float*)d_out;
  char* ws = (char*)d_ws;

  unsigned short* W1t = (unsigned short*)(ws + 0);        // 256x384 bf16
  unsigned short* W2t = (unsigned short*)(ws + 196608);   // 256x256 bf16
  unsigned short* A1  = (unsigned short*)(ws + 327680);   // 32768x384 bf16
  // ws usage ends at 25,493,504 bytes

  hipFuncSetAttribute((const void*)fused_gemm, hipFuncAttributeMaxDynamicSharedMemorySize, 163840);

  front<<<1024, 256, 0, stream>>>(pc1, pc2, W1, W2, W1t, W2t, A1, out + OUT_H_ELEMS);
  fused_gemm<<<256, 512, 163840, stream>>>(A1, W1t, W2t, b1, b2, out);
}

// Round 4
// 59.215 us; speedup vs baseline: 1.2051x; 1.2051x over previous
//
#include <hip/hip_runtime.h>

// ---------------- types / helpers ----------------
using f32x4  = __attribute__((ext_vector_type(4))) float;
using bf16x8 = __attribute__((ext_vector_type(8))) short;

struct __attribute__((packed, aligned(4))) f4a { float x, y, z, w; };  // 4B-aligned float4

__device__ __forceinline__ unsigned short f2bf(float x) {
  unsigned u = __float_as_uint(x);
  u += 0x7FFFu + ((u >> 16) & 1u);   // round-to-nearest-even
  return (unsigned short)(u >> 16);
}

// pc1: (8,1024,259)  pc2: (8,4096,131)  W1:(384,256) b1:(256) W2:(256,256) b2:(256)
// out: h (8*4096*256 fp32) then xyz2 (8*4096*3 fp32)
#define OUT_H_ELEMS 8388608

#define INSERT(e, j) { \
  bool L2 = ((e) < d2v) || ((e) == d2v && (j) < i2); \
  bool L1 = ((e) < d1 ) || ((e) == d1  && (j) < i1); \
  bool L0 = ((e) < d0 ) || ((e) == d0  && (j) < i0); \
  d2v = L1 ? d1 : (L2 ? (e) : d2v);  i2 = L1 ? i1 : (L2 ? (j) : i2); \
  d1  = L0 ? d0 : (L1 ? (e) : d1 );  i1 = L0 ? i0 : (L1 ? (j) : i1); \
  d0  = L0 ? (e) : d0;               i0 = L0 ? (j) : i0; }

// ---------------- front: weights cvt + 3-NN + inline interp + pc2 cols + xyz2 ----------------
// 1024 blocks x 512 threads; 16 lanes per query (32 queries/block). 100% occupancy cap.
__global__ __launch_bounds__(512, 8) void front(
    const float* __restrict__ pc1, const float* __restrict__ pc2,
    const float* __restrict__ W1, const float* __restrict__ W2,
    unsigned short* __restrict__ W1t, unsigned short* __restrict__ W2t,
    unsigned short* __restrict__ A1, float* __restrict__ xyzo) {
  __shared__ float4 s[1024];
  const int t = threadIdx.x;
  const int blk = blockIdx.x;
  const int b = blk >> 7;            // 8 batches x 128 blocks
  const int chunk = blk & 127;       // 32 queries per block

  // --- weight conversion: first 163840 global threads, 1 elem each ---
  int gid = blk * 512 + t;
  if (gid < 98304) {                           // W1t[n][k] = W1[k][n], 256x384
    int n = gid / 384, k = gid - n * 384;
    W1t[gid] = f2bf(W1[k * 256 + n]);
  } else if (gid < 163840) {                   // W2t[n][k] = W2[k][n], 256x256
    int id2 = gid - 98304;
    int n = id2 >> 8, k = id2 & 255;
    W2t[id2] = f2bf(W2[k * 256 + n]);
  }

  // --- stage xyz1 of this batch into LDS (2 rows/thread) ---
  const float* p1b = pc1 + (size_t)b * (1024 * 259);
  #pragma unroll
  for (int j = 0; j < 2; ++j) {
    int r = t + j * 512;
    const float* p = p1b + (size_t)r * 259;
    s[r] = make_float4(p[0], p[1], p[2], 0.f);
  }
  __syncthreads();

  const int q = chunk * 32 + (t >> 4);         // query index within batch
  const int sub = t & 15;
  const size_t qrow = (size_t)b * 4096 + q;
  const float* qp = pc2 + qrow * 131;
  const float qx = qp[0], qy = qp[1], qz = qp[2];

  // two independent top-3 chains (even/odd 16-slots) to cut dependent latency
  float d0 = 3.4e38f, d1 = 3.4e38f, d2v = 3.4e38f;
  int i0 = -1, i1 = -1, i2 = -1;
  float e0 = 3.4e38f, e1 = 3.4e38f, e2 = 3.4e38f;
  int j0 = -1, j1 = -1, j2 = -1;
  #pragma unroll 4
  for (int it = 0; it < 32; ++it) {
    const int ca = sub + it * 32;
    const int cb = ca + 16;
    float4 pa = s[ca];
    float4 pb = s[cb];
    // match numpy: ((dx*dx + dy*dy) + dz*dz), no FMA contraction
    float ax = __fsub_rn(qx, pa.x), ay = __fsub_rn(qy, pa.y), az = __fsub_rn(qz, pa.z);
    float da = __fadd_rn(__fadd_rn(__fmul_rn(ax, ax), __fmul_rn(ay, ay)), __fmul_rn(az, az));
    float bx = __fsub_rn(qx, pb.x), by = __fsub_rn(qy, pb.y), bz = __fsub_rn(qz, pb.z);
    float db = __fadd_rn(__fadd_rn(__fmul_rn(bx, bx), __fmul_rn(by, by)), __fmul_rn(bz, bz));
    { // chain A update (strict < keeps earlier index on ties)
      bool l2 = da < d2v, l1 = da < d1, l0 = da < d0;
      d2v = l1 ? d1 : (l2 ? da : d2v);  i2 = l1 ? i1 : (l2 ? ca : i2);
      d1  = l0 ? d0 : (l1 ? da : d1);   i1 = l0 ? i0 : (l1 ? ca : i1);
      d0  = l0 ? da : d0;               i0 = l0 ? ca : i0;
    }
    { // chain B update
      bool l2 = db < e2, l1 = db < e1, l0 = db < e0;
      e2 = l1 ? e1 : (l2 ? db : e2);  j2 = l1 ? j1 : (l2 ? cb : j2);
      e1 = l0 ? e0 : (l1 ? db : e1);  j1 = l0 ? j0 : (l1 ? cb : j1);
      e0 = l0 ? db : e0;              j0 = l0 ? cb : j0;
    }
  }
  // merge chain B into chain A (lexicographic (dist, idx))
  INSERT(e0, j0) INSERT(e1, j1) INSERT(e2, j2)
  // merge across the 16 lanes of this query (xor 1,2,4,8); all lanes end identical
  #pragma unroll
  for (int stp = 1; stp <= 8; stp <<= 1) {
    float f0 = __shfl_xor(d0, stp, 64);  int k0 = __shfl_xor(i0, stp, 64);
    float f1 = __shfl_xor(d1, stp, 64);  int k1 = __shfl_xor(i1, stp, 64);
    float f2 = __shfl_xor(d2v, stp, 64); int k2 = __shfl_xor(i2, stp, 64);
    INSERT(f0, k0) INSERT(f1, k1) INSERT(f2, k2)
  }
  // weights (exact reference order)
  float t0 = fmaxf(d0, 1e-7f), t1 = fmaxf(d1, 1e-7f), t2 = fmaxf(d2v, 1e-7f);
  float r0 = 1.0f / t0, r1 = 1.0f / t1, r2 = 1.0f / t2;
  float nrm = __fadd_rn(__fadd_rn(r0, r1), r2);
  float w0v = r0 / nrm, w1v = r1 / nrm, w2v = r2 / nrm;

  if (sub == 1) {
    xyzo[qrow * 3 + 0] = qx; xyzo[qrow * 3 + 1] = qy; xyzo[qrow * 3 + 2] = qz;
  }

  // --- inline interpolation: lane covers interp cols [sub*16, sub*16+16) ---
  const float* g0p = p1b + (size_t)i0 * 259 + 3 + sub * 16;
  const float* g1p = p1b + (size_t)i1 * 259 + 3 + sub * 16;
  const float* g2p = p1b + (size_t)i2 * 259 + 3 + sub * 16;
  unsigned short* arow = A1 + qrow * 384 + sub * 16;
  #pragma unroll
  for (int c4 = 0; c4 < 4; ++c4) {
    f4a a0 = *(const f4a*)(g0p + c4 * 4);
    f4a a1 = *(const f4a*)(g1p + c4 * 4);
    f4a a2 = *(const f4a*)(g2p + c4 * 4);
    ushort4 ov;
    ov.x = f2bf(fmaf(w2v, a2.x, fmaf(w1v, a1.x, w0v * a0.x)));
    ov.y = f2bf(fmaf(w2v, a2.y, fmaf(w1v, a1.y, w0v * a0.y)));
    ov.z = f2bf(fmaf(w2v, a2.z, fmaf(w1v, a1.z, w0v * a0.z)));
    ov.w = f2bf(fmaf(w2v, a2.w, fmaf(w1v, a1.w, w0v * a0.w)));
    *(ushort4*)(arow + c4 * 4) = ov;
  }
  // --- pc2 feature cols: lane covers A1 cols [256+sub*8, 256+sub*8+8) ---
  const float* gp = qp + 3 + sub * 8;
  unsigned short* arow2 = A1 + qrow * 384 + 256 + sub * 8;
  #pragma unroll
  for (int c4 = 0; c4 < 2; ++c4) {
    f4a v = *(const f4a*)(gp + c4 * 4);
    ushort4 ov;
    ov.x = f2bf(v.x); ov.y = f2bf(v.y); ov.z = f2bf(v.z); ov.w = f2bf(v.w);
    *(ushort4*)(arow2 + c4 * 4) = ov;
  }
}

// ---------------- fused two-layer MFMA GEMM (unchanged, verified) ----------------
__global__ __launch_bounds__(512, 2) void fused_gemm(
    const unsigned short* __restrict__ A1, const unsigned short* __restrict__ W1t,
    const unsigned short* __restrict__ W2t, const float* __restrict__ b1,
    const float* __restrict__ b2, float* __restrict__ out) {
  extern __shared__ char lds[];
  char* Hbuf = lds;                       // [0, 64K): H tile 128x256 bf16, row stride 512B
  char* Bb[2] = { lds + 65536, lds + 98304 };
  char* Ab[2] = { lds + 131072, lds + 147456 };

  const int t = threadIdx.x, lane = t & 63, wv = t >> 6;
  const int wm = wv >> 2, wn = wv & 3;
  const int m0 = blockIdx.x * 128;

  const int arow = t >> 2, as0 = (t & 3) * 2;
  const int brow = t >> 1, bs0 = (t & 1) * 4;
  const unsigned short* gA  = A1  + (size_t)(m0 + arow) * 384 + as0 * 8;
  const unsigned short* gB1 = W1t + (size_t)brow * 384 + bs0 * 8;
  const unsigned short* gW2 = W2t + (size_t)brow * 256 + bs0 * 8;
  int awo[2], bwo[4];
  #pragma unroll
  for (int j = 0; j < 2; ++j)
    awo[j] = arow * 128 + (((as0 + j) * 16) ^ ((arow & 7) << 4));
  #pragma unroll
  for (int j = 0; j < 4; ++j)
    bwo[j] = brow * 128 + (((bs0 + j) * 16) ^ ((brow & 7) << 4));

  f32x4 zero = {0.f, 0.f, 0.f, 0.f};
  f32x4 acc[4][4];
  #pragma unroll
  for (int i = 0; i < 4; ++i)
    #pragma unroll
    for (int j = 0; j < 4; ++j) acc[i][j] = zero;

  f32x4 ra[2], rb[4];
  #pragma unroll
  for (int j = 0; j < 2; ++j) ra[j] = *(const f32x4*)(const void*)(gA + j * 8);
  #pragma unroll
  for (int j = 0; j < 4; ++j) rb[j] = *(const f32x4*)(const void*)(gB1 + j * 8);
  #pragma unroll
  for (int j = 0; j < 2; ++j) *(f32x4*)(void*)(Ab[0] + awo[j]) = ra[j];
  #pragma unroll
  for (int j = 0; j < 4; ++j) *(f32x4*)(void*)(Bb[0] + bwo[j]) = rb[j];
  __syncthreads();

  int cur = 0;
  #pragma unroll
  for (int kt = 0; kt < 6; ++kt) {
    if (kt < 5) {
      #pragma unroll
      for (int j = 0; j < 2; ++j) ra[j] = *(const f32x4*)(const void*)(gA + (kt + 1) * 64 + j * 8);
      #pragma unroll
      for (int j = 0; j < 4; ++j) rb[j] = *(const f32x4*)(const void*)(gB1 + (kt + 1) * 64 + j * 8);
    }
    #pragma unroll
    for (int ks = 0; ks < 2; ++ks) {
      bf16x8 af[4], bfr[4];
      const int sl = ks * 4 + (lane >> 4);
      #pragma unroll
      for (int i = 0; i < 4; ++i) {
        int ar = wm * 64 + i * 16 + (lane & 15);
        af[i] = *(const bf16x8*)(void*)(Ab[cur] + ar * 128 + ((sl * 16) ^ ((ar & 7) << 4)));
        int br = wn * 64 + i * 16 + (lane & 15);
        bfr[i] = *(const bf16x8*)(void*)(Bb[cur] + br * 128 + ((sl * 16) ^ ((br & 7) << 4)));
      }
      #pragma unroll
      for (int i = 0; i < 4; ++i)
        #pragma unroll
        for (int j = 0; j < 4; ++j)
          acc[i][j] = __builtin_amdgcn_mfma_f32_16x16x32_bf16(af[i], bfr[j], acc[i][j], 0, 0, 0);
    }
    if (kt < 5) {
      #pragma unroll
      for (int j = 0; j < 2; ++j) *(f32x4*)(void*)(Ab[cur ^ 1] + awo[j]) = ra[j];
      #pragma unroll
      for (int j = 0; j < 4; ++j) *(f32x4*)(void*)(Bb[cur ^ 1] + bwo[j]) = rb[j];
    }
    __syncthreads();
    cur ^= 1;
  }

  const int colb = wn * 64 + (lane & 15);
  const int rowb = wm * 64 + ((lane >> 4) << 2);
  #pragma unroll
  for (int ni = 0; ni < 4; ++ni) {
    float bv = b1[colb + ni * 16];
    #pragma unroll
    for (int mi = 0; mi < 4; ++mi) {
      #pragma unroll
      for (int r = 0; r < 4; ++r) {
        float v = fmaxf(acc[mi][ni][r] + bv, 0.0f);
        int row = rowb + mi * 16 + r, col = colb + ni * 16;
        *(unsigned short*)(Hbuf + row * 512 + ((col * 2) ^ ((row & 15) << 4))) = f2bf(v);
        acc[mi][ni][r] = 0.0f;
      }
    }
  }
  #pragma unroll
  for (int j = 0; j < 4; ++j) rb[j] = *(const f32x4*)(const void*)(gW2 + j * 8);
  #pragma unroll
  for (int j = 0; j < 4; ++j) *(f32x4*)(void*)(Bb[0] + bwo[j]) = rb[j];
  __syncthreads();

  cur = 0;
  #pragma unroll
  for (int kt = 0; kt < 4; ++kt) {
    if (kt < 3) {
      #pragma unroll
      for (int j = 0; j < 4; ++j) rb[j] = *(const f32x4*)(const void*)(gW2 + (kt + 1) * 64 + j * 8);
    }
    #pragma unroll
    for (int ks = 0; ks < 2; ++ks) {
      bf16x8 af[4], bfr[4];
      const int sl = ks * 4 + (lane >> 4);
      #pragma unroll
      for (int i = 0; i < 4; ++i) {
        int hr = wm * 64 + i * 16 + (lane & 15);
        af[i] = *(const bf16x8*)(void*)(Hbuf + hr * 512 + ((kt * 128 + sl * 16) ^ ((hr & 15) << 4)));
        int wr = wn * 64 + i * 16 + (lane & 15);
        bfr[i] = *(const bf16x8*)(void*)(Bb[cur] + wr * 128 + ((sl * 16) ^ ((wr & 7) << 4)));
      }
      #pragma unroll
      for (int i = 0; i < 4; ++i)
        #pragma unroll
        for (int j = 0; j < 4; ++j)
          acc[i][j] = __builtin_amdgcn_mfma_f32_16x16x32_bf16(af[i], bfr[j], acc[i][j], 0, 0, 0);
    }
    if (kt < 3) {
      #pragma unroll
      for (int j = 0; j < 4; ++j) *(f32x4*)(void*)(Bb[cur ^ 1] + bwo[j]) = rb[j];
    }
    __syncthreads();
    cur ^= 1;
  }

  #pragma unroll
  for (int ni = 0; ni < 4; ++ni) {
    float bv = b2[colb + ni * 16];
    #pragma unroll
    for (int mi = 0; mi < 4; ++mi) {
      #pragma unroll
      for (int r = 0; r < 4; ++r) {
        float v = fmaxf(acc[mi][ni][r] + bv, 0.0f);
        int row = rowb + mi * 16 + r, col = colb + ni * 16;
        *(float*)(lds + row * 1024 + ((col * 4) ^ ((row & 15) << 4))) = v;
      }
    }
  }
  __syncthreads();
  #pragma unroll
  for (int q = 0; q < 16; ++q) {
    int row = q * 8 + wv;
    f32x4 v = *(const f32x4*)(void*)(lds + row * 1024 + ((lane * 16) ^ ((row & 15) << 4)));
    *(f32x4*)(out + (size_t)(m0 + row) * 256 + lane * 4) = v;
  }
}

// ---------------- launch ----------------
extern "C" void kernel_launch(void* const* d_in, const int* in_sizes, int n_in,
                              void* d_out, int out_size, void* d_ws, size_t ws_size,
                              hipStream_t stream) {
  const float* pc1 = (const float*)d_in[0];
  const float* pc2 = (const float*)d_in[1];
  const float* W1  = (const float*)d_in[2];
  const float* b1  = (const float*)d_in[3];
  const float* W2  = (const float*)d_in[4];
  const float* b2  = (const float*)d_in[5];
  float* out = (float*)d_out;
  char* ws = (char*)d_ws;

  unsigned short* W1t = (unsigned short*)(ws + 0);        // 256x384 bf16
  unsigned short* W2t = (unsigned short*)(ws + 196608);   // 256x256 bf16
  unsigned short* A1  = (unsigned short*)(ws + 327680);   // 32768x384 bf16
  // ws usage ends at 25,493,504 bytes

  hipFuncSetAttribute((const void*)fused_gemm, hipFuncAttributeMaxDynamicSharedMemorySize, 163840);

  front<<<1024, 512, 0, stream>>>(pc1, pc2, W1, W2, W1t, W2t, A1, out + OUT_H_ELEMS);
  fused_gemm<<<256, 512, 163840, stream>>>(A1, W1t, W2t, b1, b2, out);
}

// Round 5
// 58.864 us; speedup vs baseline: 1.2123x; 1.0060x over previous
//
#include <hip/hip_runtime.h>

// ---------------- types / helpers ----------------
using f32x4  = __attribute__((ext_vector_type(4))) float;
using f32x2  = __attribute__((ext_vector_type(2))) float;
using bf16x8 = __attribute__((ext_vector_type(8))) short;

struct __attribute__((packed, aligned(4))) f4a { float x, y, z, w; };  // 4B-aligned float4

__device__ __forceinline__ unsigned short f2bf(float x) {
  unsigned u = __float_as_uint(x);
  u += 0x7FFFu + ((u >> 16) & 1u);   // round-to-nearest-even
  return (unsigned short)(u >> 16);
}

// pc1: (8,1024,259)  pc2: (8,4096,131)  W1:(384,256) b1:(256) W2:(256,256) b2:(256)
// out: h (8*4096*256 fp32) then xyz2 (8*4096*3 fp32)
#define OUT_H_ELEMS 8388608

#define INSERT(e, j) { \
  bool L2 = ((e) < d2v) || ((e) == d2v && (j) < i2); \
  bool L1 = ((e) < d1 ) || ((e) == d1  && (j) < i1); \
  bool L0 = ((e) < d0 ) || ((e) == d0  && (j) < i0); \
  d2v = L1 ? d1 : (L2 ? (e) : d2v);  i2 = L1 ? i1 : (L2 ? (j) : i2); \
  d1  = L0 ? d0 : (L1 ? (e) : d1 );  i1 = L0 ? i0 : (L1 ? (j) : i1); \
  d0  = L0 ? (e) : d0;               i0 = L0 ? (j) : i0; }

// in-loop chain update: strict < keeps earliest index on ties (c strictly increasing)
#define CHAIN_UPD(dd, D0, D1, D2, I0, I1, I2, c) { \
  bool l2 = (dd) < D2, l1 = (dd) < D1, l0 = (dd) < D0; \
  D2 = l1 ? D1 : (l2 ? (dd) : D2);  I2 = l1 ? I1 : (l2 ? (c) : I2); \
  D1 = l0 ? D0 : (l1 ? (dd) : D1);  I1 = l0 ? I0 : (l1 ? (c) : I1); \
  D0 = l0 ? (dd) : D0;              I0 = l0 ? (c) : I0; }

// ---------------- front: weights cvt + 3-NN + inline interp + pc2 cols + xyz2 ----------------
// 1024 blocks x 512 threads; 16 lanes per query (32 queries/block).
// SoA LDS + packed f32 distance math + 4 selection chains per lane.
__global__ __launch_bounds__(512, 8) void front(
    const float* __restrict__ pc1, const float* __restrict__ pc2,
    const float* __restrict__ W1, const float* __restrict__ W2,
    unsigned short* __restrict__ W1t, unsigned short* __restrict__ W2t,
    unsigned short* __restrict__ A1, float* __restrict__ xyzo) {
#pragma clang fp contract(off)
  __shared__ __align__(16) float sX[1024];
  __shared__ __align__(16) float sY[1024];
  __shared__ __align__(16) float sZ[1024];
  const int t = threadIdx.x;
  const int blk = blockIdx.x;
  const int b = blk >> 7;            // 8 batches x 128 blocks
  const int chunk = blk & 127;       // 32 queries per block

  // --- weight conversion: first 163840 global threads, 1 elem each ---
  int gid = blk * 512 + t;
  if (gid < 98304) {                           // W1t[n][k] = W1[k][n], 256x384
    int n = gid / 384, k = gid - n * 384;
    W1t[gid] = f2bf(W1[k * 256 + n]);
  } else if (gid < 163840) {                   // W2t[n][k] = W2[k][n], 256x256
    int id2 = gid - 98304;
    int n = id2 >> 8, k = id2 & 255;
    W2t[id2] = f2bf(W2[k * 256 + n]);
  }

  // --- stage xyz1 of this batch into LDS, SoA (2 rows/thread) ---
  const float* p1b = pc1 + (size_t)b * (1024 * 259);
  #pragma unroll
  for (int j = 0; j < 2; ++j) {
    int r = t + j * 512;
    const float* p = p1b + (size_t)r * 259;
    sX[r] = p[0]; sY[r] = p[1]; sZ[r] = p[2];
  }
  __syncthreads();

  const int q = chunk * 32 + (t >> 4);         // query index within batch
  const int sub = t & 15;
  const size_t qrow = (size_t)b * 4096 + q;
  const float* qp = pc2 + qrow * 131;
  const float qx = qp[0], qy = qp[1], qz = qp[2];
  const f32x2 qx2 = {qx, qx}, qy2 = {qy, qy}, qz2 = {qz, qz};

  // 4 independent top-3 chains, one per element of each float4 quad
  float dA0 = 3.4e38f, dA1 = 3.4e38f, dA2 = 3.4e38f;  int iA0 = -1, iA1 = -1, iA2 = -1;
  float dB0 = 3.4e38f, dB1 = 3.4e38f, dB2 = 3.4e38f;  int iB0 = -1, iB1 = -1, iB2 = -1;
  float dC0 = 3.4e38f, dC1 = 3.4e38f, dC2 = 3.4e38f;  int iC0 = -1, iC1 = -1, iC2 = -1;
  float dD0 = 3.4e38f, dD1 = 3.4e38f, dD2 = 3.4e38f;  int iD0 = -1, iD1 = -1, iD2 = -1;

  const f32x4* sXf = (const f32x4*)sX;
  const f32x4* sYf = (const f32x4*)sY;
  const f32x4* sZf = (const f32x4*)sZ;

  #pragma unroll 4
  for (int it = 0; it < 16; ++it) {
    const int m = it * 16 + sub;       // quad index 0..255
    f32x4 xv = sXf[m], yv = sYf[m], zv = sZf[m];
    // packed exact math, numpy order: (dx*dx + dy*dy) + dz*dz, contract(off)
    f32x2 xlo = {xv[0], xv[1]}, xhi = {xv[2], xv[3]};
    f32x2 ylo = {yv[0], yv[1]}, yhi = {yv[2], yv[3]};
    f32x2 zlo = {zv[0], zv[1]}, zhi = {zv[2], zv[3]};
    f32x2 dxl = qx2 - xlo, dyl = qy2 - ylo, dzl = qz2 - zlo;
    f32x2 dxh = qx2 - xhi, dyh = qy2 - yhi, dzh = qz2 - zhi;
    f32x2 dl = (dxl * dxl + dyl * dyl) + dzl * dzl;
    f32x2 dh = (dxh * dxh + dyh * dyh) + dzh * dzh;
    const int c0 = m * 4;
    CHAIN_UPD(dl[0], dA0, dA1, dA2, iA0, iA1, iA2, c0)
    CHAIN_UPD(dl[1], dB0, dB1, dB2, iB0, iB1, iB2, c0 + 1)
    CHAIN_UPD(dh[0], dC0, dC1, dC2, iC0, iC1, iC2, c0 + 2)
    CHAIN_UPD(dh[1], dD0, dD1, dD2, iD0, iD1, iD2, c0 + 3)
  }

  // merge chains B,C,D into A (exact lexicographic)
  float d0 = dA0, d1 = dA1, d2v = dA2;  int i0 = iA0, i1 = iA1, i2 = iA2;
  INSERT(dB0, iB0) INSERT(dB1, iB1) INSERT(dB2, iB2)
  INSERT(dC0, iC0) INSERT(dC1, iC1) INSERT(dC2, iC2)
  INSERT(dD0, iD0) INSERT(dD1, iD1) INSERT(dD2, iD2)
  // merge across the 16 lanes of this query (xor 1,2,4,8); all lanes end identical
  #pragma unroll
  for (int stp = 1; stp <= 8; stp <<= 1) {
    float f0 = __shfl_xor(d0, stp, 64);  int k0 = __shfl_xor(i0, stp, 64);
    float f1 = __shfl_xor(d1, stp, 64);  int k1 = __shfl_xor(i1, stp, 64);
    float f2 = __shfl_xor(d2v, stp, 64); int k2 = __shfl_xor(i2, stp, 64);
    INSERT(f0, k0) INSERT(f1, k1) INSERT(f2, k2)
  }
  // weights (exact reference order)
  float t0 = fmaxf(d0, 1e-7f), t1 = fmaxf(d1, 1e-7f), t2 = fmaxf(d2v, 1e-7f);
  float r0 = 1.0f / t0, r1 = 1.0f / t1, r2 = 1.0f / t2;
  float nrm = (r0 + r1) + r2;
  float w0v = r0 / nrm, w1v = r1 / nrm, w2v = r2 / nrm;

  if (sub == 1) {
    xyzo[qrow * 3 + 0] = qx; xyzo[qrow * 3 + 1] = qy; xyzo[qrow * 3 + 2] = qz;
  }

  // --- inline interpolation: lane covers interp cols [sub*16, sub*16+16) ---
  const float* g0p = p1b + (size_t)i0 * 259 + 3 + sub * 16;
  const float* g1p = p1b + (size_t)i1 * 259 + 3 + sub * 16;
  const float* g2p = p1b + (size_t)i2 * 259 + 3 + sub * 16;
  unsigned short* arow = A1 + qrow * 384 + sub * 16;
  #pragma unroll
  for (int c4 = 0; c4 < 4; ++c4) {
    f4a a0 = *(const f4a*)(g0p + c4 * 4);
    f4a a1 = *(const f4a*)(g1p + c4 * 4);
    f4a a2 = *(const f4a*)(g2p + c4 * 4);
    ushort4 ov;
    ov.x = f2bf(fmaf(w2v, a2.x, fmaf(w1v, a1.x, w0v * a0.x)));
    ov.y = f2bf(fmaf(w2v, a2.y, fmaf(w1v, a1.y, w0v * a0.y)));
    ov.z = f2bf(fmaf(w2v, a2.z, fmaf(w1v, a1.z, w0v * a0.z)));
    ov.w = f2bf(fmaf(w2v, a2.w, fmaf(w1v, a1.w, w0v * a0.w)));
    *(ushort4*)(arow + c4 * 4) = ov;
  }
  // --- pc2 feature cols: lane covers A1 cols [256+sub*8, 256+sub*8+8) ---
  const float* gp = qp + 3 + sub * 8;
  unsigned short* arow2 = A1 + qrow * 384 + 256 + sub * 8;
  #pragma unroll
  for (int c4 = 0; c4 < 2; ++c4) {
    f4a v = *(const f4a*)(gp + c4 * 4);
    ushort4 ov;
    ov.x = f2bf(v.x); ov.y = f2bf(v.y); ov.z = f2bf(v.z); ov.w = f2bf(v.w);
    *(ushort4*)(arow2 + c4 * 4) = ov;
  }
}

// ---------------- fused two-layer MFMA GEMM (unchanged, verified) ----------------
__global__ __launch_bounds__(512, 2) void fused_gemm(
    const unsigned short* __restrict__ A1, const unsigned short* __restrict__ W1t,
    const unsigned short* __restrict__ W2t, const float* __restrict__ b1,
    const float* __restrict__ b2, float* __restrict__ out) {
  extern __shared__ char lds[];
  char* Hbuf = lds;                       // [0, 64K): H tile 128x256 bf16, row stride 512B
  char* Bb[2] = { lds + 65536, lds + 98304 };
  char* Ab[2] = { lds + 131072, lds + 147456 };

  const int t = threadIdx.x, lane = t & 63, wv = t >> 6;
  const int wm = wv >> 2, wn = wv & 3;
  const int m0 = blockIdx.x * 128;

  const int arow = t >> 2, as0 = (t & 3) * 2;
  const int brow = t >> 1, bs0 = (t & 1) * 4;
  const unsigned short* gA  = A1  + (size_t)(m0 + arow) * 384 + as0 * 8;
  const unsigned short* gB1 = W1t + (size_t)brow * 384 + bs0 * 8;
  const unsigned short* gW2 = W2t + (size_t)brow * 256 + bs0 * 8;
  int awo[2], bwo[4];
  #pragma unroll
  for (int j = 0; j < 2; ++j)
    awo[j] = arow * 128 + (((as0 + j) * 16) ^ ((arow & 7) << 4));
  #pragma unroll
  for (int j = 0; j < 4; ++j)
    bwo[j] = brow * 128 + (((bs0 + j) * 16) ^ ((brow & 7) << 4));

  f32x4 zero = {0.f, 0.f, 0.f, 0.f};
  f32x4 acc[4][4];
  #pragma unroll
  for (int i = 0; i < 4; ++i)
    #pragma unroll
    for (int j = 0; j < 4; ++j) acc[i][j] = zero;

  f32x4 ra[2], rb[4];
  #pragma unroll
  for (int j = 0; j < 2; ++j) ra[j] = *(const f32x4*)(const void*)(gA + j * 8);
  #pragma unroll
  for (int j = 0; j < 4; ++j) rb[j] = *(const f32x4*)(const void*)(gB1 + j * 8);
  #pragma unroll
  for (int j = 0; j < 2; ++j) *(f32x4*)(void*)(Ab[0] + awo[j]) = ra[j];
  #pragma unroll
  for (int j = 0; j < 4; ++j) *(f32x4*)(void*)(Bb[0] + bwo[j]) = rb[j];
  __syncthreads();

  int cur = 0;
  #pragma unroll
  for (int kt = 0; kt < 6; ++kt) {
    if (kt < 5) {
      #pragma unroll
      for (int j = 0; j < 2; ++j) ra[j] = *(const f32x4*)(const void*)(gA + (kt + 1) * 64 + j * 8);
      #pragma unroll
      for (int j = 0; j < 4; ++j) rb[j] = *(const f32x4*)(const void*)(gB1 + (kt + 1) * 64 + j * 8);
    }
    #pragma unroll
    for (int ks = 0; ks < 2; ++ks) {
      bf16x8 af[4], bfr[4];
      const int sl = ks * 4 + (lane >> 4);
      #pragma unroll
      for (int i = 0; i < 4; ++i) {
        int ar = wm * 64 + i * 16 + (lane & 15);
        af[i] = *(const bf16x8*)(void*)(Ab[cur] + ar * 128 + ((sl * 16) ^ ((ar & 7) << 4)));
        int br = wn * 64 + i * 16 + (lane & 15);
        bfr[i] = *(const bf16x8*)(void*)(Bb[cur] + br * 128 + ((sl * 16) ^ ((br & 7) << 4)));
      }
      #pragma unroll
      for (int i = 0; i < 4; ++i)
        #pragma unroll
        for (int j = 0; j < 4; ++j)
          acc[i][j] = __builtin_amdgcn_mfma_f32_16x16x32_bf16(af[i], bfr[j], acc[i][j], 0, 0, 0);
    }
    if (kt < 5) {
      #pragma unroll
      for (int j = 0; j < 2; ++j) *(f32x4*)(void*)(Ab[cur ^ 1] + awo[j]) = ra[j];
      #pragma unroll
      for (int j = 0; j < 4; ++j) *(f32x4*)(void*)(Bb[cur ^ 1] + bwo[j]) = rb[j];
    }
    __syncthreads();
    cur ^= 1;
  }

  const int colb = wn * 64 + (lane & 15);
  const int rowb = wm * 64 + ((lane >> 4) << 2);
  #pragma unroll
  for (int ni = 0; ni < 4; ++ni) {
    float bv = b1[colb + ni * 16];
    #pragma unroll
    for (int mi = 0; mi < 4; ++mi) {
      #pragma unroll
      for (int r = 0; r < 4; ++r) {
        float v = fmaxf(acc[mi][ni][r] + bv, 0.0f);
        int row = rowb + mi * 16 + r, col = colb + ni * 16;
        *(unsigned short*)(Hbuf + row * 512 + ((col * 2) ^ ((row & 15) << 4))) = f2bf(v);
        acc[mi][ni][r] = 0.0f;
      }
    }
  }
  #pragma unroll
  for (int j = 0; j < 4; ++j) rb[j] = *(const f32x4*)(const void*)(gW2 + j * 8);
  #pragma unroll
  for (int j = 0; j < 4; ++j) *(f32x4*)(void*)(Bb[0] + bwo[j]) = rb[j];
  __syncthreads();

  cur = 0;
  #pragma unroll
  for (int kt = 0; kt < 4; ++kt) {
    if (kt < 3) {
      #pragma unroll
      for (int j = 0; j < 4; ++j) rb[j] = *(const f32x4*)(const void*)(gW2 + (kt + 1) * 64 + j * 8);
    }
    #pragma unroll
    for (int ks = 0; ks < 2; ++ks) {
      bf16x8 af[4], bfr[4];
      const int sl = ks * 4 + (lane >> 4);
      #pragma unroll
      for (int i = 0; i < 4; ++i) {
        int hr = wm * 64 + i * 16 + (lane & 15);
        af[i] = *(const bf16x8*)(void*)(Hbuf + hr * 512 + ((kt * 128 + sl * 16) ^ ((hr & 15) << 4)));
        int wr = wn * 64 + i * 16 + (lane & 15);
        bfr[i] = *(const bf16x8*)(void*)(Bb[cur] + wr * 128 + ((sl * 16) ^ ((wr & 7) << 4)));
      }
      #pragma unroll
      for (int i = 0; i < 4; ++i)
        #pragma unroll
        for (int j = 0; j < 4; ++j)
          acc[i][j] = __builtin_amdgcn_mfma_f32_16x16x32_bf16(af[i], bfr[j], acc[i][j], 0, 0, 0);
    }
    if (kt < 3) {
      #pragma unroll
      for (int j = 0; j < 4; ++j) *(f32x4*)(void*)(Bb[cur ^ 1] + bwo[j]) = rb[j];
    }
    __syncthreads();
    cur ^= 1;
  }

  #pragma unroll
  for (int ni = 0; ni < 4; ++ni) {
    float bv = b2[colb + ni * 16];
    #pragma unroll
    for (int mi = 0; mi < 4; ++mi) {
      #pragma unroll
      for (int r = 0; r < 4; ++r) {
        float v = fmaxf(acc[mi][ni][r] + bv, 0.0f);
        int row = rowb + mi * 16 + r, col = colb + ni * 16;
        *(float*)(lds + row * 1024 + ((col * 4) ^ ((row & 15) << 4))) = v;
      }
    }
  }
  __syncthreads();
  #pragma unroll
  for (int q = 0; q < 16; ++q) {
    int row = q * 8 + wv;
    f32x4 v = *(const f32x4*)(void*)(lds + row * 1024 + ((lane * 16) ^ ((row & 15) << 4)));
    *(f32x4*)(out + (size_t)(m0 + row) * 256 + lane * 4) = v;
  }
}

// ---------------- launch ----------------
extern "C" void kernel_launch(void* const* d_in, const int* in_sizes, int n_in,
                              void* d_out, int out_size, void* d_ws, size_t ws_size,
                              hipStream_t stream) {
  const float* pc1 = (const float*)d_in[0];
  const float* pc2 = (const float*)d_in[1];
  const float* W1  = (const float*)d_in[2];
  const float* b1  = (const float*)d_in[3];
  const float* W2  = (const float*)d_in[4];
  const float* b2  = (const float*)d_in[5];
  float* out = (float*)d_out;
  char* ws = (char*)d_ws;

  unsigned short* W1t = (unsigned short*)(ws + 0);        // 256x384 bf16
  unsigned short* W2t = (unsigned short*)(ws + 196608);   // 256x256 bf16
  unsigned short* A1  = (unsigned short*)(ws + 327680);   // 32768x384 bf16
  // ws usage ends at 25,493,504 bytes

  hipFuncSetAttribute((const void*)fused_gemm, hipFuncAttributeMaxDynamicSharedMemorySize, 163840);

  front<<<1024, 512, 0, stream>>>(pc1, pc2, W1, W2, W1t, W2t, A1, out + OUT_H_ELEMS);
  fused_gemm<<<256, 512, 163840, stream>>>(A1, W1t, W2t, b1, b2, out);
}